// Round 9
// baseline (130.328 us; speedup 1.0000x reference)
//
#include <hip/hip_runtime.h>

// Problem constants (reference: shape (2,1,160,192,160), win=9)
#define BB 2
#define DD 160
#define HH 192
#define WW 160
#define HW (HH * WW)
#define PAD 4
#define TH 16
#define TW 16
#define EXTH 24             // TH + 2*PAD
#define WCS2 484            // ws channel stride (24*20 + 4 pad; %32==4, %4==0)
#define WRS2 20             // ws row stride (16 cols + 4 pad)
#define HCS2 276            // hs channel stride (16*17 + 4 pad)
#define HRS2 17             // hs row stride (odd -> staggered)
#define CHUNK 28
#define NCH 6               // ceil(DD/CHUNK)
#define NITER 36            // CHUNK + 2*PAD = 4*9 (static ring indexing)
#define WT (WW / TW)        // 10
#define HT (HH / TH)        // 12
#define NBLK (WT * HT * NCH * BB)   // 1440
#define EPS 1e-5f
#define INV_WS (1.0f / 729.0f)

// barrier that waits LDS only — never drains vmcnt (global prefetch stays in flight)
__device__ __forceinline__ void bar_lgkm() {
  asm volatile("s_waitcnt lgkmcnt(0)" ::: "memory");
  __builtin_amdgcn_s_barrier();
  asm volatile("" ::: "memory");
}

__global__ void __launch_bounds__(256) k_lncc(
    const float* __restrict__ x, const float* __restrict__ y,
    float* __restrict__ partials)
{
  // Only filtered intermediates live in LDS — no x/y plane staging.
  __shared__ __align__(16) float ws[5 * WCS2];   // W-filtered   9680 B
  __shared__ __align__(16) float hs[5 * HCS2];   // W+H-filtered 5520 B
  __shared__ float red[4];

  const int t = threadIdx.x;
  const int w0 = blockIdx.x * TW;
  const int h0 = blockIdx.y * TH;
  const int bz = blockIdx.z;
  const int b = bz / NCH;
  const int chunk = bz - b * NCH;
  const int dc0 = chunk * CHUNK;
  const int g0 = dc0 - PAD;

  const float* xb = x + (long)b * DD * HW;
  const float* yb = y + (long)b * DD * HW;

  // ---- Phase-A task (t<96): r = ext row 0..23, g4 = output quad 0..3 ----
  // Loads 12 x + 12 y floats (3 float4 each) for outputs w = 4g4..4g4+3.
  const int rA = t >> 2, g4 = t & 3;
  const int gh = h0 - PAD + rA;
  const int gw0 = w0 - PAD + 4 * g4;
  const bool actA = (t < 96);
  const bool rowOk = actA && ((unsigned)gh < (unsigned)HH);
  const bool ok0 = rowOk && ((unsigned)gw0 < (unsigned)WW);
  const bool ok1 = rowOk && ((unsigned)(gw0 + 4) < (unsigned)WW);
  const bool ok2 = rowOk && ((unsigned)(gw0 + 8) < (unsigned)WW);
  const int off0 = ok0 ? (gh * WW + gw0) : 0;
  const int off1 = ok1 ? (gh * WW + gw0 + 4) : 0;
  const int off2 = ok2 ? (gh * WW + gw0 + 8) : 0;
  const int wbaseA = rA * WRS2 + 4 * g4;       // + c*WCS2

  // ---- Phase-B task (t<80): c = channel, wB = out col ----
  const int cB = t >> 4, wB = t & 15;
  const float* const rbB = &ws[cB * WCS2 + wB];    // + i*WRS2, i=0..23
  float* const hbB = &hs[cB * HCS2 + wB];          // + h*HRS2

  // ---- Phase-C task: one output (h,w) per thread ----
  const int h4 = t >> 4, w4 = t & 15;
  const float* const hrC = &hs[h4 * HRS2 + w4];    // + c*HCS2

  // ---- D-window ring (static idx via jj), running sums ----
  float ring[9][5];
#pragma unroll
  for (int i = 0; i < 9; ++i)
#pragma unroll
    for (int c = 0; c < 5; ++c) ring[i][c] = 0.f;
  float run0 = 0.f, run1 = 0.f, run2 = 0.f, run3 = 0.f, run4 = 0.f, acc = 0.f;

  // ---- prologue: load slice k=0 (g0) into cur regs ----
  const float4 z4 = make_float4(0.f, 0.f, 0.f, 0.f);
  float4 cx0 = z4, cx1 = z4, cx2 = z4, cy0 = z4, cy1 = z4, cy2 = z4;
  if ((unsigned)g0 < (unsigned)DD) {
    const long so = (long)g0 * HW;
    cx0 = ok0 ? *(const float4*)(xb + so + off0) : z4;
    cx1 = ok1 ? *(const float4*)(xb + so + off1) : z4;
    cx2 = ok2 ? *(const float4*)(xb + so + off2) : z4;
    cy0 = ok0 ? *(const float4*)(yb + so + off0) : z4;
    cy1 = ok1 ? *(const float4*)(yb + so + off1) : z4;
    cy2 = ok2 ? *(const float4*)(yb + so + off2) : z4;
  }

  for (int ko = 0; ko < 4; ++ko) {
#pragma unroll
    for (int jj = 0; jj < 9; ++jj) {
      const int k = ko * 9 + jj;
      const int g = g0 + k;
      const bool gv = ((unsigned)g < (unsigned)DD);   // block-uniform

      // ---- Phase A: W-filter from cur regs -> ws (t<96) ----
      if (gv && actA) {
        float xa[12], ya[12];
        xa[0]=cx0.x; xa[1]=cx0.y; xa[2]=cx0.z; xa[3]=cx0.w;
        xa[4]=cx1.x; xa[5]=cx1.y; xa[6]=cx1.z; xa[7]=cx1.w;
        xa[8]=cx2.x; xa[9]=cx2.y; xa[10]=cx2.z; xa[11]=cx2.w;
        ya[0]=cy0.x; ya[1]=cy0.y; ya[2]=cy0.z; ya[3]=cy0.w;
        ya[4]=cy1.x; ya[5]=cy1.y; ya[6]=cy1.z; ya[7]=cy1.w;
        ya[8]=cy2.x; ya[9]=cy2.y; ya[10]=cy2.z; ya[11]=cy2.w;
#define EMITCH(CIDX, EXPR)                                                 \
        {                                                                  \
          float qv[12];                                                    \
          _Pragma("unroll")                                                \
          for (int i = 0; i < 12; ++i) qv[i] = (EXPR);                     \
          float o0 = ((qv[0]+qv[1])+(qv[2]+qv[3]))+                        \
                     ((qv[4]+qv[5])+(qv[6]+qv[7]))+qv[8];                  \
          float o1 = o0 + qv[9]  - qv[0];                                  \
          float o2 = o1 + qv[10] - qv[1];                                  \
          float o3 = o2 + qv[11] - qv[2];                                  \
          *(float4*)&ws[(CIDX) * WCS2 + wbaseA] = make_float4(o0,o1,o2,o3);\
        }
        EMITCH(0, xa[i])
        EMITCH(1, ya[i])
        EMITCH(2, xa[i] * xa[i])
        EMITCH(3, ya[i] * ya[i])
        EMITCH(4, xa[i] * ya[i])
#undef EMITCH
      }

      // ---- prefetch slice k+1 into nxt regs (in flight across barriers) ----
      float4 nx0 = z4, nx1 = z4, nx2 = z4, ny0 = z4, ny1 = z4, ny2 = z4;
      {
        const int gn = g + 1;
        const bool nv = (k + 1 < NITER) && ((unsigned)gn < (unsigned)DD);
        const long so = (long)gn * HW;
        nx0 = (ok0 && nv) ? *(const float4*)(xb + so + off0) : z4;
        nx1 = (ok1 && nv) ? *(const float4*)(xb + so + off1) : z4;
        nx2 = (ok2 && nv) ? *(const float4*)(xb + so + off2) : z4;
        ny0 = (ok0 && nv) ? *(const float4*)(yb + so + off0) : z4;
        ny1 = (ok1 && nv) ? *(const float4*)(yb + so + off1) : z4;
        ny2 = (ok2 && nv) ? *(const float4*)(yb + so + off2) : z4;
      }

      float hv0 = 0.f, hv1 = 0.f, hv2 = 0.f, hv3 = 0.f, hv4 = 0.f;
      if (gv) {
        bar_lgkm();  // A-writes visible; prefetch stays in flight
        // ---- Phase B: H-filter sliding columns (t<80) ----
        if (t < 80) {
          float v[EXTH];
#pragma unroll
          for (int i = 0; i < EXTH; ++i) v[i] = rbB[i * WRS2];
          float s = ((v[0] + v[1]) + (v[2] + v[3])) +
                    ((v[4] + v[5]) + (v[6] + v[7])) + v[8];
          hbB[0] = s;
#pragma unroll
          for (int h = 1; h < TH; ++h) {
            s += v[h + 8] - v[h - 1];
            hbB[h * HRS2] = s;
          }
        }
        bar_lgkm();  // B-writes visible; also protects ws WAR for next A
        // ---- Phase C: per-output channel reads ----
        hv0 = hrC[0];
        hv1 = hrC[HCS2];
        hv2 = hrC[2 * HCS2];
        hv3 = hrC[3 * HCS2];
        hv4 = hrC[4 * HCS2];
        // hs WAR vs next B protected by next iteration's bar A
      }

      // ---- D running sums; ring[jj] static -> pure VGPRs ----
      run0 += hv0 - ring[jj][0]; ring[jj][0] = hv0;
      run1 += hv1 - ring[jj][1]; ring[jj][1] = hv1;
      run2 += hv2 - ring[jj][2]; ring[jj][2] = hv2;
      run3 += hv3 - ring[jj][3]; ring[jj][3] = hv3;
      run4 += hv4 - ring[jj][4]; ring[jj][4] = hv4;

      if (k >= 8) {
        const int d = dc0 + (k - 8);
        if (d < DD) {                 // block-uniform tail guard
          float cross = fmaf(-run0 * INV_WS, run1, run4);
          float xv = fmaxf(fmaf(-run0 * INV_WS, run0, run2), EPS);
          float yv = fmaxf(fmaf(-run1 * INV_WS, run1, run3), EPS);
          acc += (cross * cross) * __builtin_amdgcn_rcpf(xv * yv);
        }
      }

      // rotate prefetch regs (renamed away by the unroll)
      cx0 = nx0; cx1 = nx1; cx2 = nx2;
      cy0 = ny0; cy1 = ny1; cy2 = ny2;
    }
  }

  // ---- block reduction ----
#pragma unroll
  for (int o = 32; o > 0; o >>= 1) acc += __shfl_down(acc, o);
  if ((t & 63) == 0) red[t >> 6] = acc;
  __syncthreads();
  if (t == 0) {
    int bid = (bz * HT + blockIdx.y) * WT + blockIdx.x;
    partials[bid] = (red[0] + red[1]) + (red[2] + red[3]);
  }
}

__global__ void __launch_bounds__(256) k_finalize(
    const float* __restrict__ partials, float* __restrict__ out)
{
  __shared__ double red[256];
  double s = 0.0;
  for (int i = threadIdx.x; i < NBLK; i += 256) s += (double)partials[i];
  red[threadIdx.x] = s;
  __syncthreads();
  for (int o = 128; o > 0; o >>= 1) {
    if (threadIdx.x < o) red[threadIdx.x] += red[threadIdx.x + o];
    __syncthreads();
  }
  if (threadIdx.x == 0) {
    const double Nvox = (double)BB * DD * HH * WW;
    out[0] = (float)(-red[0] / Nvox);
  }
}

extern "C" void kernel_launch(void* const* d_in, const int* in_sizes, int n_in,
                              void* d_out, int out_size, void* d_ws, size_t ws_size,
                              hipStream_t stream) {
  (void)in_sizes; (void)n_in; (void)out_size; (void)ws_size;
  const float* x = (const float*)d_in[0];
  const float* y = (const float*)d_in[1];
  float* out = (float*)d_out;
  float* partials = (float*)d_ws;

  dim3 grid(WT, HT, BB * NCH);
  k_lncc<<<grid, 256, 0, stream>>>(x, y, partials);
  k_finalize<<<1, 256, 0, stream>>>(partials, out);
}

// Round 10
// 81.860 us; speedup vs baseline: 1.5921x; 1.5921x over previous
//
#include <hip/hip_runtime.h>

// Problem constants (reference: shape (2,1,160,192,160), win=9)
#define BB 2
#define DD 160
#define HH 192
#define WW 160
#define HW (HH * WW)
#define PAD 4
#define TH 16
#define TW 32
#define EXTH 24             // TH + 2*PAD
#define EXTW 40             // TW + 2*PAD
#define XSTR 40             // sbuf row stride (words); rows 160B, 16B-aligned
#define APL 960             // per-array plane words (EXTH*XSTR)
#define WRS 36              // wsum row stride (32 outs + 4 pad); 36%32==4
#define WCSTR 868           // wsum channel stride; 868%32==4 (channel stagger)
#define HRS 36              // hsum row stride
#define HCSTR 580           // hsum channel stride; 580%32==4 (channel stagger)
#define CHUNK 19
#define NCH 9               // ceil(160/19): last chunk has 8 outputs
#define NITER 27            // CHUNK + 2*PAD = 3*9 (static ring indexing)
#define WT (WW / TW)        // 5
#define HT (HH / TH)        // 12
#define NBLK (WT * HT * NCH * BB)   // 1080
#define NTASK 480           // staging float4 tasks: 2 arrays x 24 rows x 10 groups
#define EPS 1e-5f
#define INV_WS (1.0f / 729.0f)

// barrier that waits LDS only — never drains vmcnt (keeps prefetch in flight)
__device__ __forceinline__ void bar_lgkm() {
  asm volatile("s_waitcnt lgkmcnt(0)" ::: "memory");
  __builtin_amdgcn_s_barrier();
  asm volatile("" ::: "memory");
}

__device__ __forceinline__ float4 f4add(float4 a, float4 b) {
  return make_float4(a.x + b.x, a.y + b.y, a.z + b.z, a.w + b.w);
}
// s + p - m, componentwise
__device__ __forceinline__ float4 f4pm(float4 s, float4 p, float4 m) {
  return make_float4(s.x + p.x - m.x, s.y + p.y - m.y,
                     s.z + p.z - m.z, s.w + p.w - m.w);
}

__global__ void __launch_bounds__(256) k_lncc(
    const float* __restrict__ x, const float* __restrict__ y,
    float* __restrict__ partials)
{
  __shared__ __align__(16) float sb[2 * APL];     // x,y ext planes  7680 B
  __shared__ __align__(16) float ws[5 * WCSTR];   // W-filtered      17360 B
  __shared__ __align__(16) float hs[5 * HCSTR];   // W+H-filtered    11600 B
  __shared__ float red[4];

  const int t = threadIdx.x;
  const int w0 = blockIdx.x * TW;
  const int h0 = blockIdx.y * TH;
  const int bz = blockIdx.z;
  const int b = bz / NCH;
  const int chunk = bz - b * NCH;
  const int dc0 = chunk * CHUNK;
  const int g0 = dc0 - PAD;

  // ---- zero planes once (OOB slots stay 0 forever) ----
  for (int i = t; i < 2 * APL; i += 256) sb[i] = 0.f;

  // ---- staging descriptors: 480 float4 tasks; thread t gets t and t+256 ----
  int la0, la1; bool tk0, tk1;
  const float* gp0; const float* gp1;
  {
    const float* bx = x + (long)b * DD * HW;
    const float* by = y + (long)b * DD * HW;
#define MKTASK(TAU, LA, TK, GP)                                           \
    {                                                                     \
      int tau = (TAU);                                                    \
      int a = tau / 240;                                                  \
      int rem = tau - 240 * a;                                            \
      int r = rem / 10;                                                   \
      int q = rem - 10 * r;                                               \
      int aa = (a < 2) ? a : 0;                                           \
      int gh = h0 - PAD + r;                                              \
      int gw = w0 - PAD + 4 * q;                                          \
      bool ok = (tau < NTASK) && ((unsigned)gh < (unsigned)HH) &&         \
                ((unsigned)gw < (unsigned)WW);                            \
      LA = aa * APL + r * XSTR + 4 * q;                                   \
      TK = ok;                                                            \
      GP = (aa ? by : bx) + (ok ? (gh * WW + gw) : 0);                    \
    }
    MKTASK(t, la0, tk0, gp0)
    MKTASK(t + 256, la1, tk1, gp1)
#undef MKTASK
  }

  // ---- P2 constants (t<192): task = (ext row r2, group qq) ----
  const int r2 = t >> 3;            // 0..23
  const int qq = t & 7;             // outputs tile w = 4qq..4qq+3
  const int rdx = r2 * XSTR + 4 * qq;   // x at [rdx..rdx+11]; y at +APL
  const int wwr = r2 * WRS + 4 * qq;    // + c*WCSTR

  // ---- P3 constants (t<80): conflict-free lane map: wq in low bits ----
  // each 8-lane group = fixed (c,hf), wq 0..7 -> 4*wq covers all 8 bank-quads
  const int wq3 = t & 7;            // 0..7
  const int hf3 = (t >> 3) & 1;     // 0..1
  const int c3 = t >> 4;            // 0..4
  const int rb3 = c3 * WCSTR + (hf3 * 8) * WRS + 4 * wq3;  // + i*WRS, i=0..15
  const int wb3 = c3 * HCSTR + (hf3 * 8) * HRS + 4 * wq3;  // + hh*HRS

  // ---- P4 constants: thread owns w-pair (2p4, 2p4+1) at row h4 ----
  const int h4 = t >> 4, p4 = t & 15;
  const int hrOff = h4 * HRS + 2 * p4;   // + c*HCSTR (float2)

  // ---- D-window ring: 9 deep x 5 ch x 2 outputs (static idx -> VGPRs) ----
  float2 rg[9][5];
#pragma unroll
  for (int i = 0; i < 9; ++i)
#pragma unroll
    for (int c = 0; c < 5; ++c) { rg[i][c].x = 0.f; rg[i][c].y = 0.f; }
  float2 rn0 = {0, 0}, rn1 = {0, 0}, rn2 = {0, 0}, rn3 = {0, 0}, rn4 = {0, 0};
  float acc = 0.f;

  __syncthreads();   // zero-init visible

  // ---- prologue: prefetch slice k=0 ----
  float4 st0 = make_float4(0, 0, 0, 0), st1 = st0;
  bool ps0 = false, ps1 = false;
  if (g0 >= 0) {
    const long so = (long)g0 * HW;
    ps0 = tk0; if (ps0) st0 = *(const float4*)(gp0 + so);
    ps1 = tk1; if (ps1) st1 = *(const float4*)(gp1 + so);
  }

  for (int ko = 0; ko < 3; ++ko) {
#pragma unroll
    for (int jj = 0; jj < 9; ++jj) {
      const int k = ko * 9 + jj;
      const int g = g0 + k;
      const bool gv = ((unsigned)g < (unsigned)DD);   // block-uniform

      // ---- store staged regs (slice k) -> planes ----
      if (gv) {
        if (ps0) *(float4*)&sb[la0] = st0;
        if (ps1) *(float4*)&sb[la1] = st1;
      }
      // ---- prefetch slice k+1 (in flight across all barriers) ----
      {
        const int gn = g + 1;
        const bool nv = (k + 1 < NITER) && ((unsigned)gn < (unsigned)DD);
        const long so = (long)gn * HW;
        ps0 = tk0 && nv; if (ps0) st0 = *(const float4*)(gp0 + so);
        ps1 = tk1 && nv; if (ps1) st1 = *(const float4*)(gp1 + so);
      }

      float2 hv0 = {0, 0}, hv1 = {0, 0}, hv2 = {0, 0}, hv3 = {0, 0}, hv4 = {0, 0};
      if (gv) {
        bar_lgkm();  // A: planes visible
        // ---- P2: W-filter; 192 tasks; contiguous b128 reads, b128 writes ----
        if (t < 192) {
          float xa[12], ya[12];
          {
            float4 X0 = *(const float4*)&sb[rdx];
            float4 X1 = *(const float4*)&sb[rdx + 4];
            float4 X2 = *(const float4*)&sb[rdx + 8];
            xa[0]=X0.x; xa[1]=X0.y; xa[2]=X0.z; xa[3]=X0.w;
            xa[4]=X1.x; xa[5]=X1.y; xa[6]=X1.z; xa[7]=X1.w;
            xa[8]=X2.x; xa[9]=X2.y; xa[10]=X2.z; xa[11]=X2.w;
            float4 Y0 = *(const float4*)&sb[APL + rdx];
            float4 Y1 = *(const float4*)&sb[APL + rdx + 4];
            float4 Y2 = *(const float4*)&sb[APL + rdx + 8];
            ya[0]=Y0.x; ya[1]=Y0.y; ya[2]=Y0.z; ya[3]=Y0.w;
            ya[4]=Y1.x; ya[5]=Y1.y; ya[6]=Y1.z; ya[7]=Y1.w;
            ya[8]=Y2.x; ya[9]=Y2.y; ya[10]=Y2.z; ya[11]=Y2.w;
          }
#define EMITCH(CIDX, EXPR)                                                 \
          {                                                                \
            float qv[12];                                                  \
            _Pragma("unroll")                                              \
            for (int i = 0; i < 12; ++i) qv[i] = (EXPR);                   \
            float o0 = ((qv[0]+qv[1])+(qv[2]+qv[3]))+                      \
                       ((qv[4]+qv[5])+(qv[6]+qv[7]))+qv[8];                \
            float o1 = o0 + qv[9]  - qv[0];                                \
            float o2 = o1 + qv[10] - qv[1];                                \
            float o3 = o2 + qv[11] - qv[2];                                \
            *(float4*)&ws[(CIDX) * WCSTR + wwr] = make_float4(o0,o1,o2,o3);\
          }
          EMITCH(0, xa[i])
          EMITCH(1, ya[i])
          EMITCH(2, xa[i] * xa[i])
          EMITCH(3, ya[i] * ya[i])
          EMITCH(4, xa[i] * ya[i])
#undef EMITCH
        }
        bar_lgkm();  // B
        // ---- P3: H-filter; 80 tasks; 4-wide sliding column sums ----
        if (t < 80) {
          float4 v[16];
#pragma unroll
          for (int i = 0; i < 9; ++i) v[i] = *(const float4*)&ws[rb3 + i * WRS];
          float4 s = f4add(f4add(f4add(f4add(v[0], v[1]), f4add(v[2], v[3])),
                                 f4add(f4add(v[4], v[5]), f4add(v[6], v[7]))),
                           v[8]);
          *(float4*)&hs[wb3] = s;
#pragma unroll
          for (int hh = 1; hh < 8; ++hh) {
            v[hh + 8] = *(const float4*)&ws[rb3 + (hh + 8) * WRS];
            s = f4pm(s, v[hh + 8], v[hh - 1]);
            *(float4*)&hs[wb3 + hh * HRS] = s;
          }
        }
        bar_lgkm();  // C
        hv0 = *(const float2*)&hs[hrOff];
        hv1 = *(const float2*)&hs[HCSTR + hrOff];
        hv2 = *(const float2*)&hs[2 * HCSTR + hrOff];
        hv3 = *(const float2*)&hs[3 * HCSTR + hrOff];
        hv4 = *(const float2*)&hs[4 * HCSTR + hrOff];
      }

      // ---- D running sums; ring[jj] static -> no register shifting ----
      rn0.x += hv0.x - rg[jj][0].x; rg[jj][0].x = hv0.x;
      rn0.y += hv0.y - rg[jj][0].y; rg[jj][0].y = hv0.y;
      rn1.x += hv1.x - rg[jj][1].x; rg[jj][1].x = hv1.x;
      rn1.y += hv1.y - rg[jj][1].y; rg[jj][1].y = hv1.y;
      rn2.x += hv2.x - rg[jj][2].x; rg[jj][2].x = hv2.x;
      rn2.y += hv2.y - rg[jj][2].y; rg[jj][2].y = hv2.y;
      rn3.x += hv3.x - rg[jj][3].x; rg[jj][3].x = hv3.x;
      rn3.y += hv3.y - rg[jj][3].y; rg[jj][3].y = hv3.y;
      rn4.x += hv4.x - rg[jj][4].x; rg[jj][4].x = hv4.x;
      rn4.y += hv4.y - rg[jj][4].y; rg[jj][4].y = hv4.y;

      if (k >= 8) {
        const int d = dc0 + (k - 8);
        if (d < DD) {                 // block-uniform tail guard
          {
            float cross = fmaf(-rn0.x * INV_WS, rn1.x, rn4.x);
            float xv = fmaxf(fmaf(-rn0.x * INV_WS, rn0.x, rn2.x), EPS);
            float yv = fmaxf(fmaf(-rn1.x * INV_WS, rn1.x, rn3.x), EPS);
            acc += (cross * cross) * __builtin_amdgcn_rcpf(xv * yv);
          }
          {
            float cross = fmaf(-rn0.y * INV_WS, rn1.y, rn4.y);
            float xv = fmaxf(fmaf(-rn0.y * INV_WS, rn0.y, rn2.y), EPS);
            float yv = fmaxf(fmaf(-rn1.y * INV_WS, rn1.y, rn3.y), EPS);
            acc += (cross * cross) * __builtin_amdgcn_rcpf(xv * yv);
          }
        }
      }
    }
  }

  // ---- block reduction ----
#pragma unroll
  for (int o = 32; o > 0; o >>= 1) acc += __shfl_down(acc, o);
  if ((t & 63) == 0) red[t >> 6] = acc;
  __syncthreads();
  if (t == 0) {
    int bid = (bz * HT + blockIdx.y) * WT + blockIdx.x;
    partials[bid] = (red[0] + red[1]) + (red[2] + red[3]);
  }
}

__global__ void __launch_bounds__(256) k_finalize(
    const float* __restrict__ partials, float* __restrict__ out)
{
  __shared__ double red[256];
  double s = 0.0;
  for (int i = threadIdx.x; i < NBLK; i += 256) s += (double)partials[i];
  red[threadIdx.x] = s;
  __syncthreads();
  for (int o = 128; o > 0; o >>= 1) {
    if (threadIdx.x < o) red[threadIdx.x] += red[threadIdx.x + o];
    __syncthreads();
  }
  if (threadIdx.x == 0) {
    const double Nvox = (double)BB * DD * HH * WW;
    out[0] = (float)(-red[0] / Nvox);
  }
}

extern "C" void kernel_launch(void* const* d_in, const int* in_sizes, int n_in,
                              void* d_out, int out_size, void* d_ws, size_t ws_size,
                              hipStream_t stream) {
  (void)in_sizes; (void)n_in; (void)out_size; (void)ws_size;
  const float* x = (const float*)d_in[0];
  const float* y = (const float*)d_in[1];
  float* out = (float*)d_out;
  float* partials = (float*)d_ws;

  dim3 grid(WT, HT, BB * NCH);
  k_lncc<<<grid, 256, 0, stream>>>(x, y, partials);
  k_finalize<<<1, 256, 0, stream>>>(partials, out);
}